// Round 1
// baseline (361.598 us; speedup 1.0000x reference)
//
#include <hip/hip_runtime.h>

#define BB 32
#define HH 512
#define WW 512
#define HW (HH * WW)
#define NPIX (BB * HH * WW)

#define TILE 32
#define HALO 4
#define TP (TILE + 2 * HALO)   // 40

// ---------------------------------------------------------------------------
// K1: per-pixel channel mean and mean-of-squares; also zero per-batch sums.
// Each thread handles 4 pixels (12 floats = 3 aligned float4 loads).
// ---------------------------------------------------------------------------
__global__ __launch_bounds__(256) void k_moments(const float4* __restrict__ x4,
                                                 float4* __restrict__ m4,
                                                 float4* __restrict__ q4,
                                                 float* __restrict__ sums) {
    int g = blockIdx.x * 256 + threadIdx.x;
    if (blockIdx.x == 0 && threadIdx.x < BB) sums[threadIdx.x] = 0.f;
    if (g >= NPIX / 4) return;
    float4 a = x4[3 * g + 0];
    float4 b = x4[3 * g + 1];
    float4 c = x4[3 * g + 2];
    const float t = 1.f / 3.f;
    float4 m, q;
    m.x = (a.x + a.y + a.z) * t;  q.x = (a.x * a.x + a.y * a.y + a.z * a.z) * t;
    m.y = (a.w + b.x + b.y) * t;  q.y = (a.w * a.w + b.x * b.x + b.y * b.y) * t;
    m.z = (b.z + b.w + c.x) * t;  q.z = (b.z * b.z + b.w * b.w + c.x * c.x) * t;
    m.w = (c.y + c.z + c.w) * t;  q.w = (c.y * c.y + c.z * c.z + c.w * c.w) * t;
    m4[g] = m;
    q4[g] = q;
}

// ---------------------------------------------------------------------------
// K2: 9x9 zero-padded cross-correlation blur of m -> lm.
// Block (32,8): 32x32 output tile, each thread computes 4 rows.
// LDS tile 40x40; per-thread 12-row register window per kx column.
// ---------------------------------------------------------------------------
__global__ __launch_bounds__(256) void k_blur_m(const float* __restrict__ src,
                                                const float* __restrict__ kw,
                                                float* __restrict__ dst) {
    __shared__ float tile[TP * TP];
    __shared__ float kk[81];
    const int tx = threadIdx.x, ty = threadIdx.y;
    const int tid = ty * 32 + tx;
    if (tid < 81) kk[tid] = kw[tid];
    const int x0 = blockIdx.x * TILE, y0 = blockIdx.y * TILE;
    const float* img = src + (size_t)blockIdx.z * HW;
    for (int i = tid; i < TP * TP; i += 256) {
        int r = i / TP, cc = i - r * TP;
        int gy = y0 + r - HALO, gx = x0 + cc - HALO;
        tile[i] = (gy >= 0 && gy < HH && gx >= 0 && gx < WW) ? img[gy * WW + gx] : 0.f;
    }
    __syncthreads();
    const int baseY = ty * 4;
    float acc0 = 0.f, acc1 = 0.f, acc2 = 0.f, acc3 = 0.f;
#pragma unroll
    for (int kx = 0; kx < 9; ++kx) {
        float c[12];
#pragma unroll
        for (int r = 0; r < 12; ++r) c[r] = tile[(baseY + r) * TP + tx + kx];
#pragma unroll
        for (int ky = 0; ky < 9; ++ky) {
            float w = kk[ky * 9 + kx];
            acc0 = fmaf(w, c[ky + 0], acc0);
            acc1 = fmaf(w, c[ky + 1], acc1);
            acc2 = fmaf(w, c[ky + 2], acc2);
            acc3 = fmaf(w, c[ky + 3], acc3);
        }
    }
    float* o = dst + (size_t)blockIdx.z * HW + (size_t)(y0 + baseY) * WW + x0 + tx;
    o[0 * WW] = acc0;
    o[1 * WW] = acc1;
    o[2 * WW] = acc2;
    o[3 * WW] = acc3;
}

// ---------------------------------------------------------------------------
// K3: build e = max(q - lm*(2m - lm), 0) in the halo tile, blur it,
// sigma = sqrt(max(.,0)); write sigma and atomically accumulate per-batch sum.
// ---------------------------------------------------------------------------
__global__ __launch_bounds__(256) void k_sigma(const float* __restrict__ m,
                                               const float* __restrict__ q,
                                               const float* __restrict__ lm,
                                               const float* __restrict__ kw,
                                               float* __restrict__ sg,
                                               float* __restrict__ sums) {
    __shared__ float tile[TP * TP];
    __shared__ float kk[81];
    __shared__ float wsum[4];
    const int tx = threadIdx.x, ty = threadIdx.y;
    const int tid = ty * 32 + tx;
    if (tid < 81) kk[tid] = kw[tid];
    const int x0 = blockIdx.x * TILE, y0 = blockIdx.y * TILE;
    const size_t boff = (size_t)blockIdx.z * HW;
    for (int i = tid; i < TP * TP; i += 256) {
        int r = i / TP, cc = i - r * TP;
        int gy = y0 + r - HALO, gx = x0 + cc - HALO;
        float e = 0.f;
        if (gy >= 0 && gy < HH && gx >= 0 && gx < WW) {
            size_t o = boff + (size_t)gy * WW + gx;
            float mm = m[o], qq = q[o], l = lm[o];
            e = fmaxf(qq - l * (2.f * mm - l), 0.f);
        }
        tile[i] = e;
    }
    __syncthreads();
    const int baseY = ty * 4;
    float acc0 = 0.f, acc1 = 0.f, acc2 = 0.f, acc3 = 0.f;
#pragma unroll
    for (int kx = 0; kx < 9; ++kx) {
        float c[12];
#pragma unroll
        for (int r = 0; r < 12; ++r) c[r] = tile[(baseY + r) * TP + tx + kx];
#pragma unroll
        for (int ky = 0; ky < 9; ++ky) {
            float w = kk[ky * 9 + kx];
            acc0 = fmaf(w, c[ky + 0], acc0);
            acc1 = fmaf(w, c[ky + 1], acc1);
            acc2 = fmaf(w, c[ky + 2], acc2);
            acc3 = fmaf(w, c[ky + 3], acc3);
        }
    }
    float s0 = sqrtf(fmaxf(acc0, 0.f));
    float s1 = sqrtf(fmaxf(acc1, 0.f));
    float s2 = sqrtf(fmaxf(acc2, 0.f));
    float s3 = sqrtf(fmaxf(acc3, 0.f));
    float* o = sg + boff + (size_t)(y0 + baseY) * WW + x0 + tx;
    o[0 * WW] = s0;
    o[1 * WW] = s1;
    o[2 * WW] = s2;
    o[3 * WW] = s3;

    float s = s0 + s1 + s2 + s3;
#pragma unroll
    for (int off = 32; off > 0; off >>= 1) s += __shfl_down(s, off);
    if ((tid & 63) == 0) wsum[tid >> 6] = s;
    __syncthreads();
    if (tid == 0) atomicAdd(&sums[blockIdx.z], wsum[0] + wsum[1] + wsum[2] + wsum[3]);
}

// ---------------------------------------------------------------------------
// K4: out = (x - lm) / max(mean_sigma_b, sigma). Thread = 4 pixels, float4 IO.
// ---------------------------------------------------------------------------
__global__ __launch_bounds__(256) void k_norm(const float4* __restrict__ x4,
                                              const float4* __restrict__ lm4,
                                              const float4* __restrict__ sg4,
                                              const float* __restrict__ sums,
                                              float4* __restrict__ out4) {
    int g = blockIdx.x * 256 + threadIdx.x;
    if (g >= NPIX / 4) return;
    int b = (g * 4) / HW;  // 4-pixel group never straddles a batch (HW % 4 == 0)
    float ms = sums[b] * (1.f / (float)HW);
    float4 l = lm4[g];
    float4 s = sg4[g];
    float i0 = 1.f / fmaxf(ms, s.x);
    float i1 = 1.f / fmaxf(ms, s.y);
    float i2 = 1.f / fmaxf(ms, s.z);
    float i3 = 1.f / fmaxf(ms, s.w);
    float4 a = x4[3 * g + 0];
    float4 bb = x4[3 * g + 1];
    float4 c = x4[3 * g + 2];
    float4 o0, o1, o2;
    o0.x = (a.x - l.x) * i0;  o0.y = (a.y - l.x) * i0;  o0.z = (a.z - l.x) * i0;
    o0.w = (a.w - l.y) * i1;  o1.x = (bb.x - l.y) * i1; o1.y = (bb.y - l.y) * i1;
    o1.z = (bb.z - l.z) * i2; o1.w = (bb.w - l.z) * i2; o2.x = (c.x - l.z) * i2;
    o2.y = (c.y - l.w) * i3;  o2.z = (c.z - l.w) * i3;  o2.w = (c.w - l.w) * i3;
    out4[3 * g + 0] = o0;
    out4[3 * g + 1] = o1;
    out4[3 * g + 2] = o2;
}

extern "C" void kernel_launch(void* const* d_in, const int* in_sizes, int n_in,
                              void* d_out, int out_size, void* d_ws, size_t ws_size,
                              hipStream_t stream) {
    const float* x = (const float*)d_in[0];
    const float* kw = (const float*)d_in[1];
    float* out = (float*)d_out;
    float* wsp = (float*)d_ws;
    float* m    = wsp + 0 * (size_t)NPIX;
    float* q    = wsp + 1 * (size_t)NPIX;
    float* lm   = wsp + 2 * (size_t)NPIX;
    float* sg   = wsp + 3 * (size_t)NPIX;
    float* sums = wsp + 4 * (size_t)NPIX;  // BB floats

    const int ngrp = NPIX / 4;             // 2097152
    k_moments<<<ngrp / 256, 256, 0, stream>>>((const float4*)x, (float4*)m, (float4*)q, sums);

    dim3 blk(32, 8);
    dim3 grd(WW / TILE, HH / TILE, BB);
    k_blur_m<<<grd, blk, 0, stream>>>(m, kw, lm);
    k_sigma<<<grd, blk, 0, stream>>>(m, q, lm, kw, sg, sums);

    k_norm<<<ngrp / 256, 256, 0, stream>>>((const float4*)x, (const float4*)lm,
                                           (const float4*)sg, sums, (float4*)out);
}

// Round 2
// 297.726 us; speedup vs baseline: 1.2145x; 1.2145x over previous
//
#include <hip/hip_runtime.h>

#define BB 32
#define HH 512
#define WW 512
#define HW (HH * WW)
#define NPIX (BB * HH * WW)

#define TILE 64
#define HALO 4
#define RG 72            // region = TILE + 2*HALO
#define RQ 18            // float4 quads per region row
#define NQ (RG * RQ)     // 1296 quads per region

// ---------------------------------------------------------------------------
// K1: per-pixel channel mean and mean-of-squares; also zero per-batch sums.
// ---------------------------------------------------------------------------
__global__ __launch_bounds__(256) void k_moments(const float4* __restrict__ x4,
                                                 float4* __restrict__ m4,
                                                 float4* __restrict__ q4,
                                                 float* __restrict__ sums) {
    int g = blockIdx.x * 256 + threadIdx.x;
    if (blockIdx.x == 0 && threadIdx.x < BB) sums[threadIdx.x] = 0.f;
    if (g >= NPIX / 4) return;
    float4 a = x4[3 * g + 0];
    float4 b = x4[3 * g + 1];
    float4 c = x4[3 * g + 2];
    const float t = 1.f / 3.f;
    float4 m, q;
    m.x = (a.x + a.y + a.z) * t;  q.x = (a.x * a.x + a.y * a.y + a.z * a.z) * t;
    m.y = (a.w + b.x + b.y) * t;  q.y = (a.w * a.w + b.x * b.x + b.y * b.y) * t;
    m.z = (b.z + b.w + c.x) * t;  q.z = (b.z * b.z + b.w * b.w + c.x * c.x) * t;
    m.w = (c.y + c.z + c.w) * t;  q.w = (c.y * c.y + c.z * c.z + c.w * c.w) * t;
    m4[g] = m;
    q4[g] = q;
}

// ---------------------------------------------------------------------------
// K2: 9x9 blur of m -> lm. 64x64 tile, 16x16 threads, 4x4 micro-tile.
// All fills float4; inner loop reads rows as 3x ds_read_b128.
// ---------------------------------------------------------------------------
__global__ __launch_bounds__(256) void k_blur_m(const float* __restrict__ src,
                                                const float* __restrict__ kw,
                                                float* __restrict__ dst) {
    __shared__ float tile[RG * RG];
    __shared__ float kk[81];
    const int tx = threadIdx.x, ty = threadIdx.y;   // 16 x 16
    const int tid = ty * 16 + tx;
    if (tid < 81) kk[tid] = kw[tid];
    const int x0 = blockIdx.x * TILE, y0 = blockIdx.y * TILE;
    const float4* s4 = (const float4*)(src + (size_t)blockIdx.z * HW);
    for (int i = tid; i < NQ; i += 256) {
        int r = i / RQ, q = i - r * RQ;
        int gy = y0 + r - HALO, gx = x0 + 4 * q - HALO;
        float4 v = make_float4(0.f, 0.f, 0.f, 0.f);
        if (gy >= 0 && gy < HH && gx >= 0 && gx < WW) v = s4[(gy * WW + gx) >> 2];
        *(float4*)&tile[r * RG + 4 * q] = v;
    }
    __syncthreads();

    float acc[4][4] = {};
    const float4* t4 = (const float4*)tile;
#pragma unroll
    for (int ky = 0; ky < 9; ++ky) {
        float w[9];
#pragma unroll
        for (int kx = 0; kx < 9; ++kx) w[kx] = kk[ky * 9 + kx];
#pragma unroll
        for (int my = 0; my < 4; ++my) {
            int rr = (4 * ty + my + ky) * RQ + tx;
            float4 a = t4[rr], b = t4[rr + 1], c = t4[rr + 2];
            float f[12] = {a.x, a.y, a.z, a.w, b.x, b.y, b.z, b.w, c.x, c.y, c.z, c.w};
#pragma unroll
            for (int kx = 0; kx < 9; ++kx)
#pragma unroll
                for (int mx = 0; mx < 4; ++mx)
                    acc[my][mx] = fmaf(w[kx], f[mx + kx], acc[my][mx]);
        }
    }
    float* dp = dst + (size_t)blockIdx.z * HW + (size_t)(y0 + 4 * ty) * WW + x0 + 4 * tx;
#pragma unroll
    for (int my = 0; my < 4; ++my)
        *(float4*)(dp + my * WW) = make_float4(acc[my][0], acc[my][1], acc[my][2], acc[my][3]);
}

// ---------------------------------------------------------------------------
// K3: build e = max(q - lm*(2m - lm), 0) tile (float4 fill), blur it,
// sigma = sqrt(max(acc,0)); write sigma; block-reduce sigma -> sums[b].
// ---------------------------------------------------------------------------
__global__ __launch_bounds__(256) void k_sigma(const float* __restrict__ m,
                                               const float* __restrict__ q,
                                               const float* __restrict__ lm,
                                               const float* __restrict__ kw,
                                               float* __restrict__ sg,
                                               float* __restrict__ sums) {
    __shared__ float tile[RG * RG];
    __shared__ float kk[81];
    __shared__ float wsum[4];
    const int tx = threadIdx.x, ty = threadIdx.y;
    const int tid = ty * 16 + tx;
    if (tid < 81) kk[tid] = kw[tid];
    const int x0 = blockIdx.x * TILE, y0 = blockIdx.y * TILE;
    const size_t boff = (size_t)blockIdx.z * HW;
    const float4* m4 = (const float4*)(m + boff);
    const float4* q4 = (const float4*)(q + boff);
    const float4* l4 = (const float4*)(lm + boff);
    for (int i = tid; i < NQ; i += 256) {
        int r = i / RQ, qd = i - r * RQ;
        int gy = y0 + r - HALO, gx = x0 + 4 * qd - HALO;
        float4 e = make_float4(0.f, 0.f, 0.f, 0.f);
        if (gy >= 0 && gy < HH && gx >= 0 && gx < WW) {
            int o = (gy * WW + gx) >> 2;
            float4 mm = m4[o], qq = q4[o], ll = l4[o];
            e.x = fmaxf(qq.x - ll.x * (2.f * mm.x - ll.x), 0.f);
            e.y = fmaxf(qq.y - ll.y * (2.f * mm.y - ll.y), 0.f);
            e.z = fmaxf(qq.z - ll.z * (2.f * mm.z - ll.z), 0.f);
            e.w = fmaxf(qq.w - ll.w * (2.f * mm.w - ll.w), 0.f);
        }
        *(float4*)&tile[r * RG + 4 * qd] = e;
    }
    __syncthreads();

    float acc[4][4] = {};
    const float4* t4 = (const float4*)tile;
#pragma unroll
    for (int ky = 0; ky < 9; ++ky) {
        float w[9];
#pragma unroll
        for (int kx = 0; kx < 9; ++kx) w[kx] = kk[ky * 9 + kx];
#pragma unroll
        for (int my = 0; my < 4; ++my) {
            int rr = (4 * ty + my + ky) * RQ + tx;
            float4 a = t4[rr], b = t4[rr + 1], c = t4[rr + 2];
            float f[12] = {a.x, a.y, a.z, a.w, b.x, b.y, b.z, b.w, c.x, c.y, c.z, c.w};
#pragma unroll
            for (int kx = 0; kx < 9; ++kx)
#pragma unroll
                for (int mx = 0; mx < 4; ++mx)
                    acc[my][mx] = fmaf(w[kx], f[mx + kx], acc[my][mx]);
        }
    }
    float s = 0.f;
    float* dp = sg + boff + (size_t)(y0 + 4 * ty) * WW + x0 + 4 * tx;
#pragma unroll
    for (int my = 0; my < 4; ++my) {
        float4 o;
        o.x = sqrtf(fmaxf(acc[my][0], 0.f));
        o.y = sqrtf(fmaxf(acc[my][1], 0.f));
        o.z = sqrtf(fmaxf(acc[my][2], 0.f));
        o.w = sqrtf(fmaxf(acc[my][3], 0.f));
        *(float4*)(dp + my * WW) = o;
        s += o.x + o.y + o.z + o.w;
    }
#pragma unroll
    for (int off = 32; off > 0; off >>= 1) s += __shfl_down(s, off);
    if ((tid & 63) == 0) wsum[tid >> 6] = s;
    __syncthreads();
    if (tid == 0) atomicAdd(&sums[blockIdx.z], wsum[0] + wsum[1] + wsum[2] + wsum[3]);
}

// ---------------------------------------------------------------------------
// K4: out = (x - lm) / max(mean_sigma_b, sigma). Thread = 4 pixels, float4 IO.
// ---------------------------------------------------------------------------
__global__ __launch_bounds__(256) void k_norm(const float4* __restrict__ x4,
                                              const float4* __restrict__ lm4,
                                              const float4* __restrict__ sg4,
                                              const float* __restrict__ sums,
                                              float4* __restrict__ out4) {
    int g = blockIdx.x * 256 + threadIdx.x;
    if (g >= NPIX / 4) return;
    int b = (g * 4) / HW;
    float ms = sums[b] * (1.f / (float)HW);
    float4 l = lm4[g];
    float4 s = sg4[g];
    float i0 = 1.f / fmaxf(ms, s.x);
    float i1 = 1.f / fmaxf(ms, s.y);
    float i2 = 1.f / fmaxf(ms, s.z);
    float i3 = 1.f / fmaxf(ms, s.w);
    float4 a = x4[3 * g + 0];
    float4 bb = x4[3 * g + 1];
    float4 c = x4[3 * g + 2];
    float4 o0, o1, o2;
    o0.x = (a.x - l.x) * i0;  o0.y = (a.y - l.x) * i0;  o0.z = (a.z - l.x) * i0;
    o0.w = (a.w - l.y) * i1;  o1.x = (bb.x - l.y) * i1; o1.y = (bb.y - l.y) * i1;
    o1.z = (bb.z - l.z) * i2; o1.w = (bb.w - l.z) * i2; o2.x = (c.x - l.z) * i2;
    o2.y = (c.y - l.w) * i3;  o2.z = (c.z - l.w) * i3;  o2.w = (c.w - l.w) * i3;
    out4[3 * g + 0] = o0;
    out4[3 * g + 1] = o1;
    out4[3 * g + 2] = o2;
}

extern "C" void kernel_launch(void* const* d_in, const int* in_sizes, int n_in,
                              void* d_out, int out_size, void* d_ws, size_t ws_size,
                              hipStream_t stream) {
    const float* x = (const float*)d_in[0];
    const float* kw = (const float*)d_in[1];
    float* out = (float*)d_out;
    float* wsp = (float*)d_ws;
    float* m    = wsp + 0 * (size_t)NPIX;
    float* q    = wsp + 1 * (size_t)NPIX;
    float* lm   = wsp + 2 * (size_t)NPIX;
    float* sg   = wsp + 3 * (size_t)NPIX;
    float* sums = wsp + 4 * (size_t)NPIX;  // BB floats

    const int ngrp = NPIX / 4;
    k_moments<<<ngrp / 256, 256, 0, stream>>>((const float4*)x, (float4*)m, (float4*)q, sums);

    dim3 blk(16, 16);
    dim3 grd(WW / TILE, HH / TILE, BB);
    k_blur_m<<<grd, blk, 0, stream>>>(m, kw, lm);
    k_sigma<<<grd, blk, 0, stream>>>(m, q, lm, kw, sg, sums);

    k_norm<<<ngrp / 256, 256, 0, stream>>>((const float4*)x, (const float4*)lm,
                                           (const float4*)sg, sums, (float4*)out);
}